// Round 10
// baseline (247.415 us; speedup 1.0000x reference)
//
#include <hip/hip_runtime.h>
#include <hip/hip_bf16.h>
#include <cstdint>
#include <cstddef>

#define DIM  128
#define NREL 8
#define SCB  4096   // elements per scan block (16 per thread)
#define CPB  20     // cols per fused block (40 KB LDS x 4 blocks/CU = 160 KB exactly)

typedef __attribute__((ext_vector_type(8))) short short8;
typedef __attribute__((ext_vector_type(4))) float f32x4;

static inline int cdiv(int a, int b){ return (a + b - 1) / b; }

// single-instruction packed fp32x2 -> bf16x2 (RNE)
__device__ inline uint32_t packrn(float lo, float hi){
    __hip_bfloat162 h = __float22bfloat162_rn(make_float2(lo, hi));
    union { __hip_bfloat162 h; uint32_t u; } v; v.h = h; return v.u;
}
__device__ inline float bf2f(uint32_t lo16){
    union { uint32_t u; float f; } v; v.u = lo16 << 16; return v.f;
}
__device__ inline float asf(int u){
    union { int i; float f; } v; v.i = u; return v.f;
}

// ---- fused prep: [0,nb4) xb convert | [nb4,nb4+eb) (col,type) histogram | [..,+128) wpk ----
__global__ __launch_bounds__(256) void k_prep(const float* __restrict__ x, unsigned short* __restrict__ xb, int n4,
                                              const int* __restrict__ col, const int* __restrict__ et, int E,
                                              int* __restrict__ cnt8, int nb4, int eb,
                                              const float* __restrict__ W1, const float* __restrict__ W2,
                                              unsigned short* __restrict__ wpk){
    int blk = blockIdx.x;
    if (blk < nb4){
        int i = blk * 256 + threadIdx.x;
        if (i >= n4) return;
        f32x4 v = __builtin_nontemporal_load((const f32x4*)x + i);   // x dead after this read
        uint2 o; o.x = packrn(v.x, v.y); o.y = packrn(v.z, v.w);
        *(uint2*)(xb + (size_t)i * 4) = o;
    } else if (blk < nb4 + eb){
        int e = (blk - nb4) * 256 + threadIdx.x;
        if (e < E) atomicAdd(&cnt8[col[e] * NREL + et[e]], 1);
    } else {
        int b = (blk - nb4 - eb) * 4 + (threadIdx.x >> 6);   // ((slot*8+nt)*4+ks), 512 total
        int lane = threadIdx.x & 63;
        int ks = b & 3, nt = (b >> 2) & 7, slot = b >> 5;
        const float* Wsrc = (slot < 8) ? (W1 + (size_t)slot * DIM * DIM)
                                       : (W2 + (size_t)(slot - 8) * DIM * DIM);
        int k0 = ks * 32 + (lane >> 4) * 8;
        int n  = nt * 16 + (lane & 15);
        uint4 ow;
        ow.x = packrn(Wsrc[(size_t)(k0 + 0) * DIM + n], Wsrc[(size_t)(k0 + 1) * DIM + n]);
        ow.y = packrn(Wsrc[(size_t)(k0 + 2) * DIM + n], Wsrc[(size_t)(k0 + 3) * DIM + n]);
        ow.z = packrn(Wsrc[(size_t)(k0 + 4) * DIM + n], Wsrc[(size_t)(k0 + 5) * DIM + n]);
        ow.w = packrn(Wsrc[(size_t)(k0 + 6) * DIM + n], Wsrc[(size_t)(k0 + 7) * DIM + n]);
        *(uint4*)(wpk + ((size_t)b * 64 + lane) * 8) = ow;
    }
}

// ---- hierarchical exclusive scan of cnt8 (M8 = N*8) -> start8[M8+1], pos8 ----
__global__ __launch_bounds__(256) void k_scan1(const int* __restrict__ cnt, int M, int* __restrict__ bsum){
    int t = threadIdx.x;
    int base = blockIdx.x * SCB + t * 16;
    int s = 0;
    #pragma unroll
    for (int k = 0; k < 16; ++k){
        int i = base + k;
        if (i < M) s += cnt[i];
    }
    #pragma unroll
    for (int o = 1; o < 64; o <<= 1) s += __shfl_xor(s, o);
    __shared__ int wsum[4];
    if ((t & 63) == 0) wsum[t >> 6] = s;
    __syncthreads();
    if (t == 0) bsum[blockIdx.x] = wsum[0] + wsum[1] + wsum[2] + wsum[3];
}

// scan3: absorbs old scan2 (per-wave redundant bsum prefix) AND emits deginv[c]
__global__ __launch_bounds__(256) void k_scan3(const int* __restrict__ cnt, int M,
                                               const int* __restrict__ bsum, int NBS,
                                               int* __restrict__ startArr, int* __restrict__ pos,
                                               float* __restrict__ deginv){
    int t = threadIdx.x;
    int base = blockIdx.x * SCB + t * 16;
    int vals[16];
    int s = 0;
    #pragma unroll
    for (int k = 0; k < 16; ++k){
        int i = base + k;
        vals[k] = (i < M) ? cnt[i] : 0;
        s += vals[k];
    }

    {
        int d0 = 0, d1 = 0;
        #pragma unroll
        for (int k = 0; k < 8; ++k){ d0 += vals[k]; d1 += vals[8 + k]; }
        int c0i = base >> 3;
        if (base < M)     deginv[c0i]     = d0 > 0 ? rsqrtf((float)d0) : 0.f;
        if (base + 8 < M) deginv[c0i + 1] = d1 > 0 ? rsqrtf((float)d1) : 0.f;
    }

    int lane = t & 63, w = t >> 6;

    int bp = 0, tp = 0;
    for (int i = lane; i < NBS; i += 64){
        int bv = bsum[i];
        if (i < (int)blockIdx.x) bp += bv;
        tp += bv;
    }
    #pragma unroll
    for (int o = 1; o < 64; o <<= 1){ bp += __shfl_xor(bp, o); tp += __shfl_xor(tp, o); }

    int v = s;
    #pragma unroll
    for (int o = 1; o < 64; o <<= 1){
        int u = __shfl_up(v, o);
        if (lane >= o) v += u;
    }
    __shared__ int wsum[4];
    if (lane == 63) wsum[w] = v;
    __syncthreads();
    int excl = v - s + bp;
    for (int i = 0; i < w; ++i) excl += wsum[i];
    #pragma unroll
    for (int k = 0; k < 16; ++k){
        int i = base + k;
        if (i < M){ startArr[i] = excl; pos[i] = excl; excl += vals[k]; }
    }
    if (blockIdx.x == (unsigned)(gridDim.x - 1) && t == 0) startArr[M] = tp;
}

// ---- place edges sorted by (col,type); coef inline ----
// meta x = cl<<20 | type<<17 | row   (row < 2^17; cl = c % CPB, 5 bits; run key = >>17)
__global__ __launch_bounds__(256) void k_place(const int* __restrict__ row, const int* __restrict__ col,
                                               const int* __restrict__ et, const float* __restrict__ ew,
                                               const float* __restrict__ deginv,
                                               int E, int* __restrict__ pos8, int2* __restrict__ pkm){
    int e = blockIdx.x * 256 + threadIdx.x;
    if (e >= E) return;
    int r = row[e], c = col[e], t = et[e];
    float cf = deginv[r] * deginv[c] * ew[e];
    int p = atomicAdd(&pos8[(c << 3) + t], 1);
    int cl = c - (c / CPB) * CPB;
    union { float f; int i; } cv; cv.f = cf;
    pkm[p] = make_int2((cl << 20) | (t << 17) | r, cv.i);
}

// ---- fused aggregate + transform conv ----
// out[c] = bias + sum_t ( sum_{e: col=c, type=t} coef_e * x[row_e] ) @ W[t]
// 512 threads = 8 waves; block owns 20 cols; 40 KB LDS -> 4 blocks/CU = 32 waves/CU.
// Phase 1 (scalar control plane): wave owns 2-3 cols; metas s_load'd; 16-deep masked
//   gather batches.
// Phase 2: wave nt=wid, M=20 via m-loop (B regs reused for both M-tiles), K=1024.
//   A1 dead lanes (al>=4) mirror A0's row -> bank profile identical to A0 (2-way, free);
//   garbage output rows 20-31 discarded in epilogue.  First 4 B fragments prefetched
//   BEFORE the phase-1 barrier (B is A-independent) -> latency rides the straggler window.
// Epilogue via 20x128 fp32 LDS tile -> coalesced stores.
template<int MODE>
__global__ __launch_bounds__(512, 8) void k_fused(const unsigned short* __restrict__ xbin,
                                                  const unsigned short* __restrict__ wpk,
                                                  const int* __restrict__ cs8,
                                                  const int2* __restrict__ pkm,
                                                  const float* __restrict__ bias,
                                                  unsigned short* __restrict__ zb,
                                                  const unsigned short* __restrict__ xb2,
                                                  const unsigned short* __restrict__ z1b2,
                                                  float* __restrict__ outS,
                                                  float* __restrict__ outH,
                                                  int N, int wslot){
    __shared__ unsigned short s[CPB * 1024];    // 40 KB: bf16 A-tile, then fp32 out-tile
    int tid = threadIdx.x;
    int wid = tid >> 6, lane = tid & 63;
    int c0 = blockIdx.x * CPB;
    int nt = wid;
    const short8* bbase = (const short8*)wpk + (size_t)wslot * 2048 + lane;

    // zero the A-tile (2560 uint4 / 512 threads)
    uint4 z4 = {0u, 0u, 0u, 0u};
    #pragma unroll
    for (int k = 0; k < 5; ++k) ((uint4*)s)[tid + 512 * k] = z4;
    __syncthreads();

#define FLUSH() *(uint32_t*)((char*)s + flushByte) = packrn(a0, a1)
#define PROC(mx, cf, u) do{                                                       \
        int fk_ = (int)(((unsigned)(mx)) >> 17);                                  \
        if (fk_ != fkPrev){                                                       \
            if (fkPrev >= 0) FLUSH();                                             \
            fkPrev = fk_;                                                         \
            flushByte = (fk_ << 8) + ((lane << 2) ^ ((fk_ << 1) & 0x70));         \
            a0 = 0.f; a1 = 0.f;                                                   \
        }                                                                         \
        a0 = fmaf(cf, bf2f((u) & 0xFFFFu), a0);                                   \
        a1 = fmaf(cf, bf2f((u) >> 16),     a1); }while(0)
#define XROW(mx) ((const uint32_t*)xbin)[((size_t)(((mx) & 0x1FFFF) << 6)) + lane]

    // ---- phase 1: 2-3 cols per wave, one contiguous edge range, scalar metas ----
    {
        int cLo = c0 + ((wid * CPB) >> 3);
        int cHi = c0 + (((wid + 1) * CPB) >> 3);
        if (cLo > N) cLo = N;
        if (cHi > N) cHi = N;
        if (cLo < cHi){
            int e  = __builtin_amdgcn_readfirstlane(cs8[cLo * NREL]);
            int eE = __builtin_amdgcn_readfirstlane(cs8[cHi * NREL]);
            int fkPrev = -1, flushByte = 0;
            float a0 = 0.f, a1 = 0.f;
            const int* __restrict__ mp = (const int*)pkm;   // uniform -> s_load path
            while (e < eE){
                int n = eE - e; if (n > 16) n = 16;
                int mxs[16]; float cfs[16]; uint32_t u[16];
                int mprev = 0;
                #pragma unroll
                for (int k = 0; k < 16; ++k){
                    int live = k < n;                    // wave-uniform
                    int raw  = mp[2 * (e + k)];          // consecutive scalar loads (pkm padded +16)
                    float rc = asf(mp[2 * (e + k) + 1]);
                    int mx = (k == 0) ? raw : (live ? raw : mprev);
                    mxs[k] = mx; mprev = mx;
                    cfs[k] = live ? rc : 0.f;            // dead slot: same run key, zero coef
                }
                #pragma unroll
                for (int k = 0; k < 16; ++k) u[k] = XROW(mxs[k]);
                __builtin_amdgcn_sched_barrier(0);
                #pragma unroll
                for (int k = 0; k < 16; ++k) PROC(mxs[k], cfs[k], u[k]);
                e += n;
            }
            if (fkPrev >= 0) FLUSH();
        }
    }
#undef PROC
#undef FLUSH
#undef XROW

    // ---- B-prefetch (t=0, ksl=0..3): A-independent, issued before the barrier so the
    //      L2 latency overlaps the phase-1 straggler window ----
    short8 Bp0 = bbase[(nt * 4 + 0) * 64];
    short8 Bp1 = bbase[(nt * 4 + 1) * 64];
    short8 Bp2 = bbase[(nt * 4 + 2) * 64];
    short8 Bp3 = bbase[(nt * 4 + 3) * 64];
    __syncthreads();

    // ---- phase 2: wave nt=wid: M=20 via m-loop (B regs reused), K=1024 ----
    f32x4 acc0 = (f32x4){0,0,0,0}, acc1 = (f32x4){0,0,0,0};

    int al = lane & 15, ak2 = (lane >> 4) * 16;
    int swz = (al & 7) << 4;
    const char* rowA0 = (const char*)s + al * 2048;
    int r1 = (al < 4) ? (16 + al) : al;                      // dead lanes mirror A0 rows:
    const char* rowA1 = (const char*)s + r1 * 2048;          // bank profile == A0 (2-way free);
                                                             // (r1&7)==al&7 keeps swz consistent
    __builtin_amdgcn_s_setprio(1);
    {   // peeled t=0 with prefetched B
        short8 Bp[4] = {Bp0, Bp1, Bp2, Bp3};
        #pragma unroll
        for (int ksl = 0; ksl < 4; ++ksl){
            int off = (ksl * 64 + ak2) ^ swz;
            short8 A0 = *(const short8*)(rowA0 + off);
            short8 A1 = *(const short8*)(rowA1 + off);
            acc0 = __builtin_amdgcn_mfma_f32_16x16x32_bf16(A0, Bp[ksl], acc0, 0, 0, 0);
            acc1 = __builtin_amdgcn_mfma_f32_16x16x32_bf16(A1, Bp[ksl], acc1, 0, 0, 0);
        }
    }
    #pragma unroll 4
    for (int ksg = 4; ksg < 32; ++ksg){
        int off = (ksg * 64 + ak2) ^ swz;
        short8 A0 = *(const short8*)(rowA0 + off);
        short8 A1 = *(const short8*)(rowA1 + off);
        int t = ksg >> 2, ksl = ksg & 3;
        short8 B = (bbase + (size_t)t * 2048)[(nt * 4 + ksl) * 64];
        acc0 = __builtin_amdgcn_mfma_f32_16x16x32_bf16(A0, B, acc0, 0, 0, 0);
        acc1 = __builtin_amdgcn_mfma_f32_16x16x32_bf16(A1, B, acc1, 0, 0, 0);
    }
    __builtin_amdgcn_s_setprio(0);
    __syncthreads();   // all A-reads done; reuse s as fp32 out-tile

    // ---- stage C tile to LDS (bias + relu applied here) ----
    float* ot = (float*)s;   // [CPB][128]
    int crb = (lane >> 4) * 4, dcl = lane & 15;
    {
        int d = nt * 16 + dcl;
        float bv = bias[d];
        #pragma unroll
        for (int r = 0; r < 4; ++r){
            int row0 = crb + r;
            float v0 = acc0[r] + bv;
            if (MODE == 0) v0 = fmaxf(v0, 0.f);
            ot[row0 * DIM + d] = v0;
            int row1 = 16 + crb + r;
            if (row1 < CPB){
                float v1 = acc1[r] + bv;
                if (MODE == 0) v1 = fmaxf(v1, 0.f);
                ot[row1 * DIM + d] = v1;
            }
        }
    }
    __syncthreads();

    // ---- coalesced output ----
    if (MODE == 0){
        if (tid < CPB * 16){
            int rowi = tid >> 4, seg = tid & 15;
            int c = c0 + rowi;
            if (c < N){
                const float* src = ot + rowi * DIM + seg * 8;
                uint4 vv;
                vv.x = packrn(src[0], src[1]);
                vv.y = packrn(src[2], src[3]);
                vv.z = packrn(src[4], src[5]);
                vv.w = packrn(src[6], src[7]);
                *(uint4*)(zb + ((size_t)c << 7) + seg * 8) = vv;
            }
        }
    } else {
        #pragma unroll
        for (int pass = 0; pass < 2; ++pass){
            int rowi = (pass == 0) ? (tid >> 5) : (16 + (tid >> 5));
            bool act = (pass == 0) || (tid < (CPB - 16) * 32);
            int c = c0 + rowi;
            if (act && c < N){
                int q = tid & 31;
                int d0 = q * 4;
                size_t o = ((size_t)c << 7) + d0;
                ushort4 xv4 = *(const ushort4*)(xb2 + o);
                ushort4 zv4 = *(const ushort4*)(z1b2 + o);
                const float* src = ot + rowi * DIM + d0;
                f32x4 S, H;
                {
                    float xv = bf2f(xv4.x), z1 = bf2f(zv4.x), v = src[0];
                    S.x = (xv + z1 + v) * 0.25f; H.x = (z1 + v) * (1.0f / 3.0f);
                }
                {
                    float xv = bf2f(xv4.y), z1 = bf2f(zv4.y), v = src[1];
                    S.y = (xv + z1 + v) * 0.25f; H.y = (z1 + v) * (1.0f / 3.0f);
                }
                {
                    float xv = bf2f(xv4.z), z1 = bf2f(zv4.z), v = src[2];
                    S.z = (xv + z1 + v) * 0.25f; H.z = (z1 + v) * (1.0f / 3.0f);
                }
                {
                    float xv = bf2f(xv4.w), z1 = bf2f(zv4.w), v = src[3];
                    S.w = (xv + z1 + v) * 0.25f; H.w = (z1 + v) * (1.0f / 3.0f);
                }
                __builtin_nontemporal_store(S, (f32x4*)(outS + o));
                __builtin_nontemporal_store(H, (f32x4*)(outH + o));
            }
        }
    }
}

extern "C" void kernel_launch(void* const* d_in, const int* in_sizes, int n_in,
                              void* d_out, int out_size, void* d_ws, size_t ws_size,
                              hipStream_t stream) {
    const float* x  = (const float*)d_in[0];
    const int*   ei = (const int*)d_in[1];
    const int*   et = (const int*)d_in[2];
    const float* ew = (const float*)d_in[3];
    const float* W1 = (const float*)d_in[4];
    const float* b1 = (const float*)d_in[5];
    const float* W2 = (const float*)d_in[6];
    const float* b2 = (const float*)d_in[7];

    int E = in_sizes[2];
    int N = in_sizes[0] / DIM;
    const int* row = ei;
    const int* col = ei + E;

    float* out = (float*)d_out;
    int ND  = N * DIM;
    int ND4 = ND / 4;
    float* zS = out;        // slot 0: z_star
    float* zH = out + ND;   // slot 1: z_sharp

    int M8   = N * NREL;
    int NBS8 = cdiv(M8, SCB);

    // ---- workspace carve (~70 MB) ----
    char* wsb = (char*)d_ws;
    size_t off = 0;
    auto take = [&](size_t bytes) -> char* {
        char* p = wsb + off;
        off = (off + bytes + 255) & ~(size_t)255;
        return p;
    };
    int*            cnt8     = (int*)           take((size_t)M8 * 4);
    int*            start8   = (int*)           take(((size_t)M8 + 1) * 4);
    int*            pos8     = (int*)           take((size_t)M8 * 4);
    int*            bsum     = (int*)           take(((size_t)NBS8 + 1) * 4);
    float*          deginv   = (float*)         take((size_t)N * 4);
    int2*           pkm      = (int2*)          take(((size_t)E + 16) * 8);       // +16: batch overread pad
    unsigned short* wpk      = (unsigned short*)take((size_t)16 * 2048 * 8 * 2);  // 512 KB
    unsigned short* xb       = (unsigned short*)take((size_t)ND * 2);
    unsigned short* z1b      = (unsigned short*)take((size_t)ND * 2);
    (void)n_in; (void)out_size; (void)ws_size;

    (void)hipMemsetAsync(cnt8, 0, (size_t)M8 * 4, stream);

    int eb  = cdiv(E, 256);
    int nb4 = cdiv(ND4, 256);
    k_prep  <<<nb4 + eb + 128, 256, 0, stream>>>(x, xb, ND4, col, et, E, cnt8, nb4, eb, W1, W2, wpk);
    k_scan1 <<<NBS8, 256, 0, stream>>>(cnt8, M8, bsum);
    k_scan3 <<<NBS8, 256, 0, stream>>>(cnt8, M8, bsum, NBS8, start8, pos8, deginv);
    k_place <<<eb, 256, 0, stream>>>(row, col, et, ew, deginv, E, pos8, pkm);

    int fb = cdiv(N, CPB);
    // conv1: z1b = bf16(relu(agg(x) @ W1 + b1))
    k_fused<0><<<fb, 512, 0, stream>>>(xb, wpk, start8, pkm, b1, z1b, nullptr, nullptr, nullptr, nullptr, N, 0);
    // conv2: fused z_star/z_sharp from xb, z1b, agg(z1b) @ W2 + b2
    k_fused<1><<<fb, 512, 0, stream>>>(z1b, wpk, start8, pkm, b2, nullptr, xb, z1b, zS, zH, N, 8);
}

// Round 11
// 244.807 us; speedup vs baseline: 1.0107x; 1.0107x over previous
//
#include <hip/hip_runtime.h>
#include <hip/hip_bf16.h>
#include <cstdint>
#include <cstddef>

#define DIM  128
#define NREL 8
#define SCB  4096   // elements per scan block (16 per thread)
#define CPB  20     // cols per fused block (40 KB LDS x 4 blocks/CU = 160 KB exactly)

typedef __attribute__((ext_vector_type(8))) short short8;
typedef __attribute__((ext_vector_type(4))) float f32x4;

static inline int cdiv(int a, int b){ return (a + b - 1) / b; }

// single-instruction packed fp32x2 -> bf16x2 (RNE)
__device__ inline uint32_t packrn(float lo, float hi){
    __hip_bfloat162 h = __float22bfloat162_rn(make_float2(lo, hi));
    union { __hip_bfloat162 h; uint32_t u; } v; v.h = h; return v.u;
}
__device__ inline float bf2f(uint32_t lo16){
    union { uint32_t u; float f; } v; v.u = lo16 << 16; return v.f;
}
__device__ inline float asf(int u){
    union { int i; float f; } v; v.i = u; return v.f;
}

// ---- prep: [0,eb) (col,type) histogram | [eb,eb+128) wpk pack ----
// (xb conversion pass ELIMINATED: conv1 now gathers f32 x directly)
__global__ __launch_bounds__(256) void k_prep(const int* __restrict__ col, const int* __restrict__ et, int E,
                                              int* __restrict__ cnt8, int eb,
                                              const float* __restrict__ W1, const float* __restrict__ W2,
                                              unsigned short* __restrict__ wpk){
    int blk = blockIdx.x;
    if (blk < eb){
        int e = blk * 256 + threadIdx.x;
        if (e < E) atomicAdd(&cnt8[col[e] * NREL + et[e]], 1);
    } else {
        int b = (blk - eb) * 4 + (threadIdx.x >> 6);   // ((slot*8+nt)*4+ks), 512 total
        int lane = threadIdx.x & 63;
        int ks = b & 3, nt = (b >> 2) & 7, slot = b >> 5;
        const float* Wsrc = (slot < 8) ? (W1 + (size_t)slot * DIM * DIM)
                                       : (W2 + (size_t)(slot - 8) * DIM * DIM);
        int k0 = ks * 32 + (lane >> 4) * 8;
        int n  = nt * 16 + (lane & 15);
        uint4 ow;
        ow.x = packrn(Wsrc[(size_t)(k0 + 0) * DIM + n], Wsrc[(size_t)(k0 + 1) * DIM + n]);
        ow.y = packrn(Wsrc[(size_t)(k0 + 2) * DIM + n], Wsrc[(size_t)(k0 + 3) * DIM + n]);
        ow.z = packrn(Wsrc[(size_t)(k0 + 4) * DIM + n], Wsrc[(size_t)(k0 + 5) * DIM + n]);
        ow.w = packrn(Wsrc[(size_t)(k0 + 6) * DIM + n], Wsrc[(size_t)(k0 + 7) * DIM + n]);
        *(uint4*)(wpk + ((size_t)b * 64 + lane) * 8) = ow;
    }
}

// ---- hierarchical exclusive scan of cnt8 (M8 = N*8) -> start8[M8+1], pos8 ----
__global__ __launch_bounds__(256) void k_scan1(const int* __restrict__ cnt, int M, int* __restrict__ bsum){
    int t = threadIdx.x;
    int base = blockIdx.x * SCB + t * 16;
    int s = 0;
    #pragma unroll
    for (int k = 0; k < 16; ++k){
        int i = base + k;
        if (i < M) s += cnt[i];
    }
    #pragma unroll
    for (int o = 1; o < 64; o <<= 1) s += __shfl_xor(s, o);
    __shared__ int wsum[4];
    if ((t & 63) == 0) wsum[t >> 6] = s;
    __syncthreads();
    if (t == 0) bsum[blockIdx.x] = wsum[0] + wsum[1] + wsum[2] + wsum[3];
}

// scan3: absorbs old scan2 (per-wave redundant bsum prefix) AND emits deginv[c]
__global__ __launch_bounds__(256) void k_scan3(const int* __restrict__ cnt, int M,
                                               const int* __restrict__ bsum, int NBS,
                                               int* __restrict__ startArr, int* __restrict__ pos,
                                               float* __restrict__ deginv){
    int t = threadIdx.x;
    int base = blockIdx.x * SCB + t * 16;
    int vals[16];
    int s = 0;
    #pragma unroll
    for (int k = 0; k < 16; ++k){
        int i = base + k;
        vals[k] = (i < M) ? cnt[i] : 0;
        s += vals[k];
    }

    {
        int d0 = 0, d1 = 0;
        #pragma unroll
        for (int k = 0; k < 8; ++k){ d0 += vals[k]; d1 += vals[8 + k]; }
        int c0i = base >> 3;
        if (base < M)     deginv[c0i]     = d0 > 0 ? rsqrtf((float)d0) : 0.f;
        if (base + 8 < M) deginv[c0i + 1] = d1 > 0 ? rsqrtf((float)d1) : 0.f;
    }

    int lane = t & 63, w = t >> 6;

    int bp = 0, tp = 0;
    for (int i = lane; i < NBS; i += 64){
        int bv = bsum[i];
        if (i < (int)blockIdx.x) bp += bv;
        tp += bv;
    }
    #pragma unroll
    for (int o = 1; o < 64; o <<= 1){ bp += __shfl_xor(bp, o); tp += __shfl_xor(tp, o); }

    int v = s;
    #pragma unroll
    for (int o = 1; o < 64; o <<= 1){
        int u = __shfl_up(v, o);
        if (lane >= o) v += u;
    }
    __shared__ int wsum[4];
    if (lane == 63) wsum[w] = v;
    __syncthreads();
    int excl = v - s + bp;
    for (int i = 0; i < w; ++i) excl += wsum[i];
    #pragma unroll
    for (int k = 0; k < 16; ++k){
        int i = base + k;
        if (i < M){ startArr[i] = excl; pos[i] = excl; excl += vals[k]; }
    }
    if (blockIdx.x == (unsigned)(gridDim.x - 1) && t == 0) startArr[M] = tp;
}

// ---- place edges sorted by (col,type); coef inline ----
// meta x = cl<<20 | type<<17 | row   (row < 2^17; cl = c % CPB, 5 bits; run key = >>17)
__global__ __launch_bounds__(256) void k_place(const int* __restrict__ row, const int* __restrict__ col,
                                               const int* __restrict__ et, const float* __restrict__ ew,
                                               const float* __restrict__ deginv,
                                               int E, int* __restrict__ pos8, int2* __restrict__ pkm){
    int e = blockIdx.x * 256 + threadIdx.x;
    if (e >= E) return;
    int r = row[e], c = col[e], t = et[e];
    float cf = deginv[r] * deginv[c] * ew[e];
    int p = atomicAdd(&pos8[(c << 3) + t], 1);
    int cl = c - (c / CPB) * CPB;
    union { float f; int i; } cv; cv.f = cf;
    pkm[p] = make_int2((cl << 20) | (t << 17) | r, cv.i);
}

// ---- fused aggregate + transform conv ----
// out[c] = bias + sum_t ( sum_{e: col=c, type=t} coef_e * src[row_e] ) @ W[t]
// 512 threads = 8 waves; block owns 20 cols; 40 KB LDS -> 4 blocks/CU = 32 waves/CU.
// MODE 0: gather f32 x directly (float2/lane) — no pre-converted bf16 copy needed;
//         PROC consumes f32 directly (no bf2f unpack). Output z1b bf16.
// MODE 1: gather bf16 z1b (dword/lane); epilogue reads f32 x + bf16 z1 -> outS/outH.
// Phase 1 (scalar control plane): wave owns 2-3 cols; metas s_load'd; 16-deep masked
//   gather batches.  Phase 2: wave nt=wid, M=20 via m-loop (B regs reused), K=1024;
//   first 4 B fragments prefetched before the phase-1 barrier.
template<int MODE>
__global__ __launch_bounds__(512, 8) void k_fused(const unsigned short* __restrict__ gb,
                                                  const float* __restrict__ xf,
                                                  const unsigned short* __restrict__ wpk,
                                                  const int* __restrict__ cs8,
                                                  const int2* __restrict__ pkm,
                                                  const float* __restrict__ bias,
                                                  unsigned short* __restrict__ zb,
                                                  const unsigned short* __restrict__ z1b2,
                                                  float* __restrict__ outS,
                                                  float* __restrict__ outH,
                                                  int N, int wslot){
    __shared__ unsigned short s[CPB * 1024];    // 40 KB: bf16 A-tile, then fp32 out-tile
    int tid = threadIdx.x;
    int wid = tid >> 6, lane = tid & 63;
    int c0 = blockIdx.x * CPB;
    int nt = wid;
    const short8* bbase = (const short8*)wpk + (size_t)wslot * 2048 + lane;

    // zero the A-tile (2560 uint4 / 512 threads)
    uint4 z4 = {0u, 0u, 0u, 0u};
    #pragma unroll
    for (int k = 0; k < 5; ++k) ((uint4*)s)[tid + 512 * k] = z4;
    __syncthreads();

#define FLUSH() *(uint32_t*)((char*)s + flushByte) = packrn(a0, a1)
#define PROC(mx, cf, va, vb) do{                                                  \
        int fk_ = (int)(((unsigned)(mx)) >> 17);                                  \
        if (fk_ != fkPrev){                                                       \
            if (fkPrev >= 0) FLUSH();                                             \
            fkPrev = fk_;                                                         \
            flushByte = (fk_ << 8) + ((lane << 2) ^ ((fk_ << 1) & 0x70));         \
            a0 = 0.f; a1 = 0.f;                                                   \
        }                                                                         \
        a0 = fmaf(cf, va, a0);                                                    \
        a1 = fmaf(cf, vb, a1); }while(0)

    // ---- phase 1: 2-3 cols per wave, one contiguous edge range, scalar metas ----
    {
        int cLo = c0 + ((wid * CPB) >> 3);
        int cHi = c0 + (((wid + 1) * CPB) >> 3);
        if (cLo > N) cLo = N;
        if (cHi > N) cHi = N;
        if (cLo < cHi){
            int e  = __builtin_amdgcn_readfirstlane(cs8[cLo * NREL]);
            int eE = __builtin_amdgcn_readfirstlane(cs8[cHi * NREL]);
            int fkPrev = -1, flushByte = 0;
            float a0 = 0.f, a1 = 0.f;
            const int* __restrict__ mp = (const int*)pkm;   // uniform -> s_load path
            while (e < eE){
                int n = eE - e; if (n > 16) n = 16;
                int mxs[16]; float cfs[16];
                int mprev = 0;
                #pragma unroll
                for (int k = 0; k < 16; ++k){
                    int live = k < n;                    // wave-uniform
                    int raw  = mp[2 * (e + k)];          // consecutive scalar loads (pkm padded +16)
                    float rc = asf(mp[2 * (e + k) + 1]);
                    int mx = (k == 0) ? raw : (live ? raw : mprev);
                    mxs[k] = mx; mprev = mx;
                    cfs[k] = live ? rc : 0.f;            // dead slot: same run key, zero coef
                }
                if (MODE == 0){
                    float2 u[16];
                    #pragma unroll
                    for (int k = 0; k < 16; ++k)
                        u[k] = ((const float2*)xf)[((mxs[k] & 0x1FFFF) << 6) + lane];
                    __builtin_amdgcn_sched_barrier(0);
                    #pragma unroll
                    for (int k = 0; k < 16; ++k) PROC(mxs[k], cfs[k], u[k].x, u[k].y);
                } else {
                    uint32_t u[16];
                    #pragma unroll
                    for (int k = 0; k < 16; ++k)
                        u[k] = ((const uint32_t*)gb)[((mxs[k] & 0x1FFFF) << 6) + lane];
                    __builtin_amdgcn_sched_barrier(0);
                    #pragma unroll
                    for (int k = 0; k < 16; ++k)
                        PROC(mxs[k], cfs[k], bf2f(u[k] & 0xFFFFu), bf2f(u[k] >> 16));
                }
                e += n;
            }
            if (fkPrev >= 0) FLUSH();
        }
    }
#undef PROC
#undef FLUSH

    // ---- B-prefetch (t=0): A-independent, L2 latency rides the phase-1 straggler window ----
    short8 Bp0 = bbase[(nt * 4 + 0) * 64];
    short8 Bp1 = bbase[(nt * 4 + 1) * 64];
    short8 Bp2 = bbase[(nt * 4 + 2) * 64];
    short8 Bp3 = bbase[(nt * 4 + 3) * 64];
    __syncthreads();

    // ---- phase 2: wave nt=wid: M=20 via m-loop (B regs reused), K=1024 ----
    f32x4 acc0 = (f32x4){0,0,0,0}, acc1 = (f32x4){0,0,0,0};

    int al = lane & 15, ak2 = (lane >> 4) * 16;
    int swz = (al & 7) << 4;
    const char* rowA0 = (const char*)s + al * 2048;
    int r1 = (al < 4) ? (16 + al) : al;                      // dead lanes mirror A0 rows
    const char* rowA1 = (const char*)s + r1 * 2048;

    __builtin_amdgcn_s_setprio(1);
    {   // peeled t=0 with prefetched B
        short8 Bp[4] = {Bp0, Bp1, Bp2, Bp3};
        #pragma unroll
        for (int ksl = 0; ksl < 4; ++ksl){
            int off = (ksl * 64 + ak2) ^ swz;
            short8 A0 = *(const short8*)(rowA0 + off);
            short8 A1 = *(const short8*)(rowA1 + off);
            acc0 = __builtin_amdgcn_mfma_f32_16x16x32_bf16(A0, Bp[ksl], acc0, 0, 0, 0);
            acc1 = __builtin_amdgcn_mfma_f32_16x16x32_bf16(A1, Bp[ksl], acc1, 0, 0, 0);
        }
    }
    #pragma unroll 4
    for (int ksg = 4; ksg < 32; ++ksg){
        int off = (ksg * 64 + ak2) ^ swz;
        short8 A0 = *(const short8*)(rowA0 + off);
        short8 A1 = *(const short8*)(rowA1 + off);
        int t = ksg >> 2, ksl = ksg & 3;
        short8 B = (bbase + (size_t)t * 2048)[(nt * 4 + ksl) * 64];
        acc0 = __builtin_amdgcn_mfma_f32_16x16x32_bf16(A0, B, acc0, 0, 0, 0);
        acc1 = __builtin_amdgcn_mfma_f32_16x16x32_bf16(A1, B, acc1, 0, 0, 0);
    }
    __builtin_amdgcn_s_setprio(0);
    __syncthreads();   // all A-reads done; reuse s as fp32 out-tile

    // ---- stage C tile to LDS (bias + relu applied here) ----
    float* ot = (float*)s;   // [CPB][128]
    int crb = (lane >> 4) * 4, dcl = lane & 15;
    {
        int d = nt * 16 + dcl;
        float bv = bias[d];
        #pragma unroll
        for (int r = 0; r < 4; ++r){
            int row0 = crb + r;
            float v0 = acc0[r] + bv;
            if (MODE == 0) v0 = fmaxf(v0, 0.f);
            ot[row0 * DIM + d] = v0;
            int row1 = 16 + crb + r;
            if (row1 < CPB){
                float v1 = acc1[r] + bv;
                if (MODE == 0) v1 = fmaxf(v1, 0.f);
                ot[row1 * DIM + d] = v1;
            }
        }
    }
    __syncthreads();

    // ---- coalesced output ----
    if (MODE == 0){
        if (tid < CPB * 16){
            int rowi = tid >> 4, seg = tid & 15;
            int c = c0 + rowi;
            if (c < N){
                const float* src = ot + rowi * DIM + seg * 8;
                uint4 vv;
                vv.x = packrn(src[0], src[1]);
                vv.y = packrn(src[2], src[3]);
                vv.z = packrn(src[4], src[5]);
                vv.w = packrn(src[6], src[7]);
                *(uint4*)(zb + ((size_t)c << 7) + seg * 8) = vv;
            }
        }
    } else {
        #pragma unroll
        for (int pass = 0; pass < 2; ++pass){
            int rowi = (pass == 0) ? (tid >> 5) : (16 + (tid >> 5));
            bool act = (pass == 0) || (tid < (CPB - 16) * 32);
            int c = c0 + rowi;
            if (act && c < N){
                int q = tid & 31;
                int d0 = q * 4;
                size_t o = ((size_t)c << 7) + d0;
                f32x4 xv = *(const f32x4*)(xf + o);          // f32 x (exact, no pre-rounding)
                ushort4 zv4 = *(const ushort4*)(z1b2 + o);
                const float* src = ot + rowi * DIM + d0;
                f32x4 S, H;
                {
                    float z1 = bf2f(zv4.x), v = src[0];
                    S.x = (xv.x + z1 + v) * 0.25f; H.x = (z1 + v) * (1.0f / 3.0f);
                }
                {
                    float z1 = bf2f(zv4.y), v = src[1];
                    S.y = (xv.y + z1 + v) * 0.25f; H.y = (z1 + v) * (1.0f / 3.0f);
                }
                {
                    float z1 = bf2f(zv4.z), v = src[2];
                    S.z = (xv.z + z1 + v) * 0.25f; H.z = (z1 + v) * (1.0f / 3.0f);
                }
                {
                    float z1 = bf2f(zv4.w), v = src[3];
                    S.w = (xv.w + z1 + v) * 0.25f; H.w = (z1 + v) * (1.0f / 3.0f);
                }
                __builtin_nontemporal_store(S, (f32x4*)(outS + o));
                __builtin_nontemporal_store(H, (f32x4*)(outH + o));
            }
        }
    }
}

extern "C" void kernel_launch(void* const* d_in, const int* in_sizes, int n_in,
                              void* d_out, int out_size, void* d_ws, size_t ws_size,
                              hipStream_t stream) {
    const float* x  = (const float*)d_in[0];
    const int*   ei = (const int*)d_in[1];
    const int*   et = (const int*)d_in[2];
    const float* ew = (const float*)d_in[3];
    const float* W1 = (const float*)d_in[4];
    const float* b1 = (const float*)d_in[5];
    const float* W2 = (const float*)d_in[6];
    const float* b2 = (const float*)d_in[7];

    int E = in_sizes[2];
    int N = in_sizes[0] / DIM;
    const int* row = ei;
    const int* col = ei + E;

    float* out = (float*)d_out;
    int ND  = N * DIM;
    float* zS = out;        // slot 0: z_star
    float* zH = out + ND;   // slot 1: z_sharp

    int M8   = N * NREL;
    int NBS8 = cdiv(M8, SCB);

    // ---- workspace carve ----
    char* wsb = (char*)d_ws;
    size_t off = 0;
    auto take = [&](size_t bytes) -> char* {
        char* p = wsb + off;
        off = (off + bytes + 255) & ~(size_t)255;
        return p;
    };
    int*            cnt8     = (int*)           take((size_t)M8 * 4);
    int*            start8   = (int*)           take(((size_t)M8 + 1) * 4);
    int*            pos8     = (int*)           take((size_t)M8 * 4);
    int*            bsum     = (int*)           take(((size_t)NBS8 + 1) * 4);
    float*          deginv   = (float*)         take((size_t)N * 4);
    int2*           pkm      = (int2*)          take(((size_t)E + 16) * 8);       // +16: batch overread pad
    unsigned short* wpk      = (unsigned short*)take((size_t)16 * 2048 * 8 * 2);  // 512 KB
    unsigned short* z1b      = (unsigned short*)take((size_t)ND * 2);
    (void)n_in; (void)out_size; (void)ws_size;

    (void)hipMemsetAsync(cnt8, 0, (size_t)M8 * 4, stream);

    int eb = cdiv(E, 256);
    k_prep  <<<eb + 128, 256, 0, stream>>>(col, et, E, cnt8, eb, W1, W2, wpk);
    k_scan1 <<<NBS8, 256, 0, stream>>>(cnt8, M8, bsum);
    k_scan3 <<<NBS8, 256, 0, stream>>>(cnt8, M8, bsum, NBS8, start8, pos8, deginv);
    k_place <<<eb, 256, 0, stream>>>(row, col, et, ew, deginv, E, pos8, pkm);

    int fb = cdiv(N, CPB);
    // conv1: z1b = bf16(relu(agg(x_f32) @ W1 + b1)) — gathers f32 x directly
    k_fused<0><<<fb, 512, 0, stream>>>(nullptr, x, wpk, start8, pkm, b1, z1b, nullptr, nullptr, nullptr, N, 0);
    // conv2: fused z_star/z_sharp from f32 x, bf16 z1b, agg(z1b) @ W2 + b2
    k_fused<1><<<fb, 512, 0, stream>>>(z1b, x, wpk, start8, pkm, b2, nullptr, z1b, zS, zH, N, 8);
}